// Round 14
// baseline (188.535 us; speedup 1.0000x reference)
//
#include <hip/hip_runtime.h>

#define VOCAB 40
#define SEQ 128
#define THREADS 256
#define ROWS_PB 32   // 32 rows per block; wave w owns rows 8w..8w+7
#define GSTRIDE 41   // 40 bins + 1 pad word per row histogram

// Load phase: each wave VMEM instruction reads a CONTIGUOUS 1 KB row-pair
// (lanes 0-31 -> row 2k, lanes 32-63 -> row 2k+1, 16 B/lane) instead of 8
// scattered 128 B segments -> coalescer/MSHR-friendly cold streaming.
// Histogram: group-shared full-word hist per row, ds_add atomics (r12).
// Extraction: lane l of 8-lane group owns bins 5l..5l+4; 9-shuffle packed
// reduce (identical to r12, which passed).

__global__ __launch_bounds__(THREADS) void char_dist_kernel(
    const int* __restrict__ x, float* __restrict__ out, int batch) {
  __shared__ unsigned int hist[ROWS_PB * GSTRIDE];
  const int tid = threadIdx.x;
  const int lane = tid & 63;     // lane within wave
  const int wv = tid >> 6;       // wave within block (0..3)
  const int l = tid & 7;         // lane within extraction group
  const int g = tid >> 3;        // extraction group = row within block (0..31)
  const int blockRow = blockIdx.x * ROWS_PB;

  // Zero own row's bins (extraction-group ownership).
  unsigned int* gh = &hist[g * GSTRIDE];
  const int b0 = 5 * l;
#pragma unroll
  for (int j = 0; j < 5; ++j) gh[b0 + j] = 0u;
  __builtin_amdgcn_wave_barrier();

  // Contiguous load + atomic histogram. Instruction k covers rows
  // {8wv+2k, 8wv+2k+1}: per-lane int4 index = (blockRow+8wv)*32 + 64k + lane.
  const int half = lane >> 5;    // 0: even row of pair, 1: odd row
  const long wrowbase = (long)blockRow + wv * 8;
  const int4* wp = reinterpret_cast<const int4*>(x) + wrowbase * 32 + lane;
#pragma unroll
  for (int k = 0; k < 4; ++k) {
    const int rrel = wv * 8 + 2 * k + half;
    if ((long)blockRow + rrel < batch) {
      const int4 t = wp[k * 64];
      unsigned int* hh = &hist[rrel * GSTRIDE];
      atomicAdd(&hh[t.x], 1u);
      atomicAdd(&hh[t.y], 1u);
      atomicAdd(&hh[t.z], 1u);
      atomicAdd(&hh[t.w], 1u);
    }
  }
  __builtin_amdgcn_wave_barrier();

  // Extraction (r12-identical): lane l reads its 5 bins of row g.
  const int row = blockRow + g;
  const bool active = row < batch;

  int c0 = (int)gh[b0 + 0];
  int c1 = (int)gh[b0 + 1];
  int c2 = (int)gh[b0 + 2];
  int c3 = (int)gh[b0 + 3];
  int c4 = (int)gh[b0 + 4];
  if (l == 0) c0 = 0;  // bin 0 = padding, excluded from all stats

  int total = 0, uniq = 0, maxc = 0, minc = 255, letters = 0, digits = 0;
#define STAT(j, cc)                                                          \
  {                                                                          \
    const int bin = b0 + (j);                                                \
    total += (cc);                                                           \
    uniq += ((cc) > 0) ? 1 : 0;                                              \
    maxc = max(maxc, (cc));                                                  \
    minc = min(minc, ((cc) > 0) ? (cc) : 255);                               \
    letters += (bin <= 26) ? (cc) : 0;                                       \
    digits += (bin >= 27 && bin <= 36) ? (cc) : 0;                           \
  }
  STAT(0, c0) STAT(1, c1) STAT(2, c2) STAT(3, c3) STAT(4, c4)
#undef STAT

  unsigned int S = (unsigned)total | ((unsigned)letters << 8) |
                   ((unsigned)digits << 16) | ((unsigned)uniq << 24);
#pragma unroll
  for (int d = 1; d < 8; d <<= 1) {
    S += __shfl_xor(S, d);
    maxc = max(maxc, __shfl_xor(maxc, d));
    minc = min(minc, __shfl_xor(minc, d));
  }

  if (active && l == 0) {
    const int totalR = (int)(S & 0xFFu);
    const int lettersR = (int)((S >> 8) & 0xFFu);
    const int digitsR = (int)((S >> 16) & 0xFFu);
    const int uniqR = (int)(S >> 24);
    const int specialR = totalR - lettersR - digitsR;
    float f0, f1, f2, f3, f4, f5;
    if (totalR > 0) {
      const float inv = 1.0f / (float)totalR;
      f0 = (float)uniqR * (1.0f / (float)VOCAB);
      f1 = (float)maxc * inv;
      f2 = (float)minc * inv;
      f3 = (float)lettersR * inv;
      f4 = (float)digitsR * inv;
      f5 = (float)specialR * inv;
    } else {
      f0 = f1 = f2 = f3 = f4 = f5 = 0.0f;
    }
    float2* o = reinterpret_cast<float2*>(out + (long)row * 6);
    o[0] = make_float2(f0, f1);
    o[1] = make_float2(f2, f3);
    o[2] = make_float2(f4, f5);
  }
}

extern "C" void kernel_launch(void* const* d_in, const int* in_sizes, int n_in,
                              void* d_out, int out_size, void* d_ws, size_t ws_size,
                              hipStream_t stream) {
  const int* x = (const int*)d_in[0];
  float* out = (float*)d_out;
  const int batch = in_sizes[0] / SEQ;
  const int blocks = (batch + ROWS_PB - 1) / ROWS_PB;
  char_dist_kernel<<<blocks, THREADS, 0, stream>>>(x, out, batch);
}